// Round 1
// baseline (244.329 us; speedup 1.0000x reference)
//
#include <hip/hip_runtime.h>
#include <hip/hip_bf16.h>

typedef __attribute__((ext_vector_type(8))) short short8;
typedef __attribute__((ext_vector_type(4))) float f32x4;

#define T_    2048
#define QKVN  1536
#define DOUT_ 1024

__device__ __forceinline__ unsigned short bf16r(float f) {
    union { float f; unsigned u; } v; v.f = f;
    unsigned r = v.u + 0x7fffu + ((v.u >> 16) & 1u);   // round-to-nearest-even
    return (unsigned short)(r >> 16);
}
__device__ __forceinline__ float fbf16(short s) {
    union { unsigned u; float f; } v; v.u = ((unsigned)(unsigned short)s) << 16;
    return v.f;
}

// dst[n*K + k] = bf16(src[k*N + n]); i = n*K + k so writes are coalesced
__global__ void k_transpose(const float* __restrict__ src, short* __restrict__ dst,
                            int K, int N) {
    int total = K * N;
    for (int i = blockIdx.x * blockDim.x + threadIdx.x; i < total;
         i += gridDim.x * blockDim.x) {
        int k = i % K;
        int n = i / K;
        dst[i] = (short)bf16r(src[(size_t)k * N + n]);
    }
}

// in-place RoPE on Q (16 heads) and K (4 heads) columns of QKV [4096][1536]
__global__ void k_rope(short* __restrict__ qkv, const float* __restrict__ cosT,
                       const float* __restrict__ sinT) {
    int row = blockIdx.x;              // 0..4095 (b*T + t)
    int t   = row & (T_ - 1);
    int h   = threadIdx.x >> 5;        // 0..19
    int d   = threadIdx.x & 31;
    int base = (h < 16) ? (h * 64) : (1024 + (h - 16) * 64);
    float cd = cosT[t * 64 + d];
    float sd = sinT[t * 64 + d];
    short* p = qkv + (size_t)row * QKVN + base;
    float a = fbf16(p[d]);
    float b = fbf16(p[d + 32]);
    p[d]      = (short)bf16r(a * cd - b * sd);
    p[d + 32] = (short)bf16r(b * cd + a * sd);
}

// C[M][N] = A[M][K] * Bt[N][K]^T ; A is f32 (converted while staging) or bf16.
// 128x128 tile, BK=64, 4 waves (2x2), each wave 64x64 via 4x4 16x16x32 MFMA frags.
template <typename AT, int CF32>
__global__ __launch_bounds__(256)
void k_gemm(const AT* __restrict__ A, const short* __restrict__ Bt,
            void* __restrict__ Cv, int M, int N, int K) {
    __shared__ __align__(16) short As[128][72];   // +8 pad -> 2-way bank alias (free)
    __shared__ __align__(16) short Bs[128][72];
    int tid = threadIdx.x;
    int l = tid & 63, w = tid >> 6;
    int lr = l & 15, lg = l >> 4;
    int m0 = blockIdx.x * 128;
    int n0 = blockIdx.y * 128;
    int wr = (w >> 1) * 64, wc = (w & 1) * 64;

    f32x4 z = {0.f, 0.f, 0.f, 0.f};
    f32x4 acc[4][4];
#pragma unroll
    for (int m = 0; m < 4; m++)
#pragma unroll
        for (int n = 0; n < 4; n++) acc[m][n] = z;

    for (int k0 = 0; k0 < K; k0 += 64) {
        // stage A-tile [128][64] and B-tile [128][64] (8 bf16 = 16B per chunk)
#pragma unroll
        for (int c = tid; c < 1024; c += 256) {
            int row = c >> 3, seg = c & 7;
            uint4 aval;
            if constexpr (sizeof(AT) == 4) {
                const float* s = (const float*)A + (size_t)(m0 + row) * K + k0 + seg * 8;
                float4 f1 = *(const float4*)s;
                float4 f2 = *(const float4*)(s + 4);
                aval.x = (unsigned)bf16r(f1.x) | ((unsigned)bf16r(f1.y) << 16);
                aval.y = (unsigned)bf16r(f1.z) | ((unsigned)bf16r(f1.w) << 16);
                aval.z = (unsigned)bf16r(f2.x) | ((unsigned)bf16r(f2.y) << 16);
                aval.w = (unsigned)bf16r(f2.z) | ((unsigned)bf16r(f2.w) << 16);
            } else {
                aval = *(const uint4*)((const short*)A + (size_t)(m0 + row) * K + k0 + seg * 8);
            }
            *(uint4*)&As[row][seg * 8] = aval;
            *(uint4*)&Bs[row][seg * 8] =
                *(const uint4*)(Bt + (size_t)(n0 + row) * K + k0 + seg * 8);
        }
        __syncthreads();
#pragma unroll
        for (int kk = 0; kk < 2; kk++) {
            short8 af[4], bf[4];
#pragma unroll
            for (int m = 0; m < 4; m++)
                af[m] = *(const short8*)&As[wr + m * 16 + lr][kk * 32 + lg * 8];
#pragma unroll
            for (int n = 0; n < 4; n++)
                bf[n] = *(const short8*)&Bs[wc + n * 16 + lr][kk * 32 + lg * 8];
#pragma unroll
            for (int m = 0; m < 4; m++)
#pragma unroll
                for (int n = 0; n < 4; n++)
                    acc[m][n] = __builtin_amdgcn_mfma_f32_16x16x32_bf16(
                        af[m], bf[n], acc[m][n], 0, 0, 0);
        }
        __syncthreads();
    }
    // epilogue: D row=(lg*4+r), col=lr within each 16x16 frag
#pragma unroll
    for (int m = 0; m < 4; m++)
#pragma unroll
        for (int n = 0; n < 4; n++)
#pragma unroll
            for (int r = 0; r < 4; r++) {
                int row = m0 + wr + m * 16 + lg * 4 + r;
                int col = n0 + wc + n * 16 + lr;
                float v = acc[m][n][r];
                if (CF32) ((float*)Cv)[(size_t)row * N + col] = v;
                else      ((short*)Cv)[(size_t)row * N + col] = (short)bf16r(v);
            }
}

// Flash attention. Block: (b, g, 32 q-rows); 4 waves = 4 hpg heads sharing K/V LDS.
// scale = 1/sqrt(T) per the reference.
__global__ __launch_bounds__(256)
void k_attn(const short* __restrict__ qkv, short* __restrict__ attn) {
    __shared__ __align__(16) short Ks[32][72];
    __shared__ __align__(16) short Vs[64][40];    // V transposed: Vs[d][s]
    __shared__ __align__(16) short Ps[4][32][40]; // per-wave P tile
    int id = blockIdx.x;                 // 0..511
    int b = id & 1;
    int g = (id >> 1) & 3;
    int j = id >> 3;                     // 0..63
    int qt = (j < 32) ? (2 * j) : (63 - 2 * (j - 32));  // work-balanced pairing
    int q0 = qt * 32;
    int tid = threadIdx.x;
    int w = tid >> 6;                    // hpg head
    int l = tid & 63;
    int lr = l & 15, lg = l >> 4;
    const float scale = 0.022097086912079608f;  // 1/sqrt(2048)
    size_t rowbase = (size_t)b * T_ * QKVN;
    int qcol = g * 256 + w * 64;
    int kcol = 1024 + g * 64;
    int vcol = 1280 + g * 64;

    // Q fragments in registers: rows q0+m*16+lr, k(=d) = kk*32 + lg*8 .. +7
    short8 qf[2][2];
#pragma unroll
    for (int m = 0; m < 2; m++)
#pragma unroll
        for (int kk = 0; kk < 2; kk++)
            qf[m][kk] = *(const short8*)(qkv + rowbase +
                          (size_t)(q0 + m * 16 + lr) * QKVN + qcol + kk * 32 + lg * 8);

    f32x4 z = {0.f, 0.f, 0.f, 0.f};
    f32x4 acc[2][4];
    float mrun[2][4], lrun[2][4];
#pragma unroll
    for (int m = 0; m < 2; m++) {
#pragma unroll
        for (int n = 0; n < 4; n++) acc[m][n] = z;
#pragma unroll
        for (int r = 0; r < 4; r++) { mrun[m][r] = -__builtin_inff(); lrun[m][r] = 0.f; }
    }

    int ntiles = q0 / 32 + 1;
    for (int kt = 0; kt < ntiles; kt++) {
        int s0 = kt * 32;
        {   // stage K [32][64] and V^T [64][32]; 256 threads = 32 rows x 8 segs
            int row = tid >> 3, seg = tid & 7;
            *(uint4*)&Ks[row][seg * 8] =
                *(const uint4*)(qkv + rowbase + (size_t)(s0 + row) * QKVN + kcol + seg * 8);
            uint4 v8 = *(const uint4*)(qkv + rowbase + (size_t)(s0 + row) * QKVN + vcol + seg * 8);
            const short* vp = (const short*)&v8;
#pragma unroll
            for (int x = 0; x < 8; x++) Vs[seg * 8 + x][row] = vp[x];
        }
        __syncthreads();

        // S = Q K^T : B-frag lane: K[c*16+lr][kk*32+lg*8..+7]
        short8 kf[2][2];
#pragma unroll
        for (int c = 0; c < 2; c++)
#pragma unroll
            for (int kk = 0; kk < 2; kk++)
                kf[c][kk] = *(const short8*)&Ks[c * 16 + lr][kk * 32 + lg * 8];
        f32x4 sfr[2][2];
#pragma unroll
        for (int m = 0; m < 2; m++)
#pragma unroll
            for (int c = 0; c < 2; c++) {
                sfr[m][c] = z;
#pragma unroll
                for (int kk = 0; kk < 2; kk++)
                    sfr[m][c] = __builtin_amdgcn_mfma_f32_16x16x32_bf16(
                        qf[m][kk], kf[c][kk], sfr[m][c], 0, 0, 0);
            }

        // online softmax per q-row (rows live in lg-group; cols across 16 lanes)
#pragma unroll
        for (int m = 0; m < 2; m++) {
#pragma unroll
            for (int r = 0; r < 4; r++) {
                int qrow = q0 + m * 16 + lg * 4 + r;
                float v0 = sfr[m][0][r] * scale;
                float v1 = sfr[m][1][r] * scale;
                if (s0 + lr      > qrow) v0 = -__builtin_inff();
                if (s0 + 16 + lr > qrow) v1 = -__builtin_inff();
                float mx = fmaxf(v0, v1);
#pragma unroll
                for (int sh = 1; sh < 16; sh <<= 1) mx = fmaxf(mx, __shfl_xor(mx, sh, 64));
                float mnew = fmaxf(mrun[m][r], mx);
                float p0 = __expf(v0 - mnew);
                float p1 = __expf(v1 - mnew);
                float sum = p0 + p1;
#pragma unroll
                for (int sh = 1; sh < 16; sh <<= 1) sum += __shfl_xor(sum, sh, 64);
                float alpha = __expf(mrun[m][r] - mnew);
                lrun[m][r] = lrun[m][r] * alpha + sum;
                mrun[m][r] = mnew;
#pragma unroll
                for (int n = 0; n < 4; n++) acc[m][n][r] *= alpha;
                Ps[w][m * 16 + lg * 4 + r][lr]      = (short)bf16r(p0);
                Ps[w][m * 16 + lg * 4 + r][16 + lr] = (short)bf16r(p1);
            }
        }

        // O += P V : A=P[32q x 32s], B=V[32s x 64d] read from Vs[d][s]
        short8 pa[2], vb[4];
#pragma unroll
        for (int m = 0; m < 2; m++)
            pa[m] = *(const short8*)&Ps[w][m * 16 + lr][lg * 8];
#pragma unroll
        for (int n = 0; n < 4; n++)
            vb[n] = *(const short8*)&Vs[n * 16 + lr][lg * 8];
#pragma unroll
        for (int m = 0; m < 2; m++)
#pragma unroll
            for (int n = 0; n < 4; n++)
                acc[m][n] = __builtin_amdgcn_mfma_f32_16x16x32_bf16(
                    pa[m], vb[n], acc[m][n], 0, 0, 0);
        __syncthreads();
    }

    // write O/l as bf16 into attn [4096][1024], col = head*64 + d
#pragma unroll
    for (int m = 0; m < 2; m++)
#pragma unroll
        for (int n = 0; n < 4; n++)
#pragma unroll
            for (int r = 0; r < 4; r++) {
                int row = q0 + m * 16 + lg * 4 + r;
                int col = g * 256 + w * 64 + n * 16 + lr;
                attn[((size_t)b * T_ + row) * DOUT_ + col] =
                    (short)bf16r(acc[m][n][r] / lrun[m][r]);
            }
}

extern "C" void kernel_launch(void* const* d_in, const int* in_sizes, int n_in,
                              void* d_out, int out_size, void* d_ws, size_t ws_size,
                              hipStream_t stream) {
    const float* x    = (const float*)d_in[0];
    const float* Wq   = (const float*)d_in[1];
    const float* Wk   = (const float*)d_in[2];
    const float* Wv   = (const float*)d_in[3];
    const float* Wo   = (const float*)d_in[4];
    const float* cosT = (const float*)d_in[5];
    const float* sinT = (const float*)d_in[6];

    char* ws = (char*)d_ws;
    short* WT  = (short*)(ws);              // [1536][1024] bf16 (WqT|WkT|WvT)
    short* WoT = (short*)(ws + 3145728);    // [1024][1024] bf16
    short* QKV = (short*)(ws + 5242880);    // [4096][1536] bf16
    short* ATT = (short*)(ws + 17825792);   // [4096][1024] bf16
    // total ws use: 25 MB

    k_transpose<<<2048, 256, 0, stream>>>(Wq, WT, 1024, 1024);
    k_transpose<<<512,  256, 0, stream>>>(Wk, WT + 1024 * 1024, 1024, 256);
    k_transpose<<<512,  256, 0, stream>>>(Wv, WT + 1280 * 1024, 1024, 256);
    k_transpose<<<2048, 256, 0, stream>>>(Wo, WoT, 1024, 1024);

    k_gemm<float, 0><<<dim3(32, 12), 256, 0, stream>>>(x, WT, (void*)QKV, 4096, 1536, 1024);
    k_rope<<<4096, 640, 0, stream>>>(QKV, cosT, sinT);
    k_attn<<<512, 256, 0, stream>>>(QKV, ATT);
    k_gemm<short, 1><<<dim3(32, 8), 256, 0, stream>>>(ATT, WoT, d_out, 4096, 1024, 1024);
}

// Round 2
// 178.844 us; speedup vs baseline: 1.3662x; 1.3662x over previous
//
#include <hip/hip_runtime.h>
#include <hip/hip_bf16.h>

typedef __attribute__((ext_vector_type(8))) short short8;
typedef __attribute__((ext_vector_type(4))) float f32x4;

#define T_    2048
#define QKVN  1536
#define DOUT_ 1024

__device__ __forceinline__ unsigned short bf16r(float f) {
    union { float f; unsigned u; } v; v.f = f;
    unsigned r = v.u + 0x7fffu + ((v.u >> 16) & 1u);   // round-to-nearest-even
    return (unsigned short)(r >> 16);
}
__device__ __forceinline__ float fbf16(short s) {
    union { unsigned u; float f; } v; v.u = ((unsigned)(unsigned short)s) << 16;
    return v.f;
}

// src [K][N] f32  ->  dst [N][K] bf16, LDS-tiled 64x64 (coalesced both sides)
__global__ __launch_bounds__(256)
void k_transpose(const float* __restrict__ src, short* __restrict__ dst,
                 int K, int N) {
    __shared__ short tile[64][72];
    int tk = blockIdx.x * 64;
    int tn = blockIdx.y * 64;
    int t = threadIdx.x;
    int r4 = t >> 6, c = t & 63;
#pragma unroll
    for (int i = 0; i < 16; i++) {
        int row = i * 4 + r4;
        tile[c][row] = (short)bf16r(src[(size_t)(tk + row) * N + tn + c]);
    }
    __syncthreads();
    int row = t >> 2, seg = t & 3;
    short8 a = *(const short8*)&tile[row][seg * 16];
    short8 b = *(const short8*)&tile[row][seg * 16 + 8];
    *(short8*)&dst[(size_t)(tn + row) * K + tk + seg * 16]     = a;
    *(short8*)&dst[(size_t)(tn + row) * K + tk + seg * 16 + 8] = b;
}

// in-place RoPE on Q (16 heads) and K (4 heads) columns of QKV [4096][1536]
__global__ void k_rope(short* __restrict__ qkv, const float* __restrict__ cosT,
                       const float* __restrict__ sinT) {
    int row = blockIdx.x;
    int t   = row & (T_ - 1);
    int h   = threadIdx.x >> 5;        // 0..19
    int d   = threadIdx.x & 31;
    int base = (h < 16) ? (h * 64) : (1024 + (h - 16) * 64);
    float cd = cosT[t * 64 + d];
    float sd = sinT[t * 64 + d];
    short* p = qkv + (size_t)row * QKVN + base;
    float a = fbf16(p[d]);
    float b = fbf16(p[d + 32]);
    p[d]      = (short)bf16r(a * cd - b * sd);
    p[d + 32] = (short)bf16r(b * cd + a * sd);
}

// C[M][N] = A[M][K] * Bt[N][K]^T (unchanged from R1)
template <typename AT, int CF32>
__global__ __launch_bounds__(256)
void k_gemm(const AT* __restrict__ A, const short* __restrict__ Bt,
            void* __restrict__ Cv, int M, int N, int K) {
    __shared__ __align__(16) short As[128][72];
    __shared__ __align__(16) short Bs[128][72];
    int tid = threadIdx.x;
    int l = tid & 63, w = tid >> 6;
    int lr = l & 15, lg = l >> 4;
    int m0 = blockIdx.x * 128;
    int n0 = blockIdx.y * 128;
    int wr = (w >> 1) * 64, wc = (w & 1) * 64;

    f32x4 z = {0.f, 0.f, 0.f, 0.f};
    f32x4 acc[4][4];
#pragma unroll
    for (int m = 0; m < 4; m++)
#pragma unroll
        for (int n = 0; n < 4; n++) acc[m][n] = z;

    for (int k0 = 0; k0 < K; k0 += 64) {
#pragma unroll
        for (int c = tid; c < 1024; c += 256) {
            int row = c >> 3, seg = c & 7;
            uint4 aval;
            if constexpr (sizeof(AT) == 4) {
                const float* s = (const float*)A + (size_t)(m0 + row) * K + k0 + seg * 8;
                float4 f1 = *(const float4*)s;
                float4 f2 = *(const float4*)(s + 4);
                aval.x = (unsigned)bf16r(f1.x) | ((unsigned)bf16r(f1.y) << 16);
                aval.y = (unsigned)bf16r(f1.z) | ((unsigned)bf16r(f1.w) << 16);
                aval.z = (unsigned)bf16r(f2.x) | ((unsigned)bf16r(f2.y) << 16);
                aval.w = (unsigned)bf16r(f2.z) | ((unsigned)bf16r(f2.w) << 16);
            } else {
                aval = *(const uint4*)((const short*)A + (size_t)(m0 + row) * K + k0 + seg * 8);
            }
            *(uint4*)&As[row][seg * 8] = aval;
            *(uint4*)&Bs[row][seg * 8] =
                *(const uint4*)(Bt + (size_t)(n0 + row) * K + k0 + seg * 8);
        }
        __syncthreads();
#pragma unroll
        for (int kk = 0; kk < 2; kk++) {
            short8 af[4], bf[4];
#pragma unroll
            for (int m = 0; m < 4; m++)
                af[m] = *(const short8*)&As[wr + m * 16 + lr][kk * 32 + lg * 8];
#pragma unroll
            for (int n = 0; n < 4; n++)
                bf[n] = *(const short8*)&Bs[wc + n * 16 + lr][kk * 32 + lg * 8];
#pragma unroll
            for (int m = 0; m < 4; m++)
#pragma unroll
                for (int n = 0; n < 4; n++)
                    acc[m][n] = __builtin_amdgcn_mfma_f32_16x16x32_bf16(
                        af[m], bf[n], acc[m][n], 0, 0, 0);
        }
        __syncthreads();
    }
#pragma unroll
    for (int m = 0; m < 4; m++)
#pragma unroll
        for (int n = 0; n < 4; n++)
#pragma unroll
            for (int r = 0; r < 4; r++) {
                int row = m0 + wr + m * 16 + lg * 4 + r;
                int col = n0 + wc + n * 16 + lr;
                float v = acc[m][n][r];
                if (CF32) ((float*)Cv)[(size_t)row * N + col] = v;
                else      ((short*)Cv)[(size_t)row * N + col] = (short)bf16r(v);
            }
}

// Flash attention v2: KVBLK=64, dbuf K/V 1-barrier/tile, async-stage split,
// exp2-domain prescaled Q, deferred l-sum, packed P with slot permutation.
__global__ __launch_bounds__(256)
void k_attn(const short* __restrict__ qkv, short* __restrict__ attn) {
    __shared__ __align__(16) short Ks[2][64][72];
    __shared__ __align__(16) short Vs[2][64][72];   // Vs[buf][d][slot]
    __shared__ __align__(16) short Ps[4][32][72];   // Ps[wave][q][slot]
    int id = blockIdx.x;
    int b = id & 1;
    int g = (id >> 1) & 3;
    int j = id >> 3;
    int qt = (j < 32) ? (2 * j) : (63 - 2 * (j - 32));  // work-balanced pairing
    int q0 = qt * 32;
    int tid = threadIdx.x;
    int w = tid >> 6;
    int l = tid & 63;
    int lr = l & 15, lg = l >> 4;
    const float s2 = 0.03187928f;   // log2(e)/sqrt(2048): exp2-domain score scale
    size_t rowbase = (size_t)b * T_ * QKVN;
    int qcol = g * 256 + w * 64;
    int kcol = 1024 + g * 64;
    int vcol = 1280 + g * 64;

    // Q fragments, pre-scaled by s2
    short8 qf[2][2];
#pragma unroll
    for (int m = 0; m < 2; m++)
#pragma unroll
        for (int kk = 0; kk < 2; kk++) {
            short8 raw = *(const short8*)(qkv + rowbase +
                          (size_t)(q0 + m * 16 + lr) * QKVN + qcol + kk * 32 + lg * 8);
            short8 sc;
#pragma unroll
            for (int x = 0; x < 8; x++) sc[x] = (short)bf16r(fbf16(raw[x]) * s2);
            qf[m][kk] = sc;
        }

    int srow = tid >> 2, sp = tid & 3;       // staging: 4 threads/row, 32B each
    uint4 sK0, sK1, sV0, sV1;
    // slot permutation pi(s): pairs (s, s+16) -> (2i, 2i+1) within each 32-half
    int pc = (srow & 32) + ((srow & 15) << 1) + ((srow >> 4) & 1);

    auto STAGE_LOAD = [&](int s0) {
        const uint4* ks = (const uint4*)(qkv + rowbase + (size_t)(s0 + srow) * QKVN + kcol);
        sK0 = ks[sp * 2]; sK1 = ks[sp * 2 + 1];
        const uint4* vs = (const uint4*)(qkv + rowbase + (size_t)(s0 + srow) * QKVN + vcol);
        sV0 = vs[sp * 2]; sV1 = vs[sp * 2 + 1];
    };
    auto STAGE_WRITE = [&](int bu) {
        *(uint4*)&Ks[bu][srow][sp * 16]     = sK0;
        *(uint4*)&Ks[bu][srow][sp * 16 + 8] = sK1;
        const short* vp0 = (const short*)&sV0;
        const short* vp1 = (const short*)&sV1;
#pragma unroll
        for (int x = 0; x < 8; x++) Vs[bu][sp * 16 + x][pc]     = vp0[x];
#pragma unroll
        for (int x = 0; x < 8; x++) Vs[bu][sp * 16 + 8 + x][pc] = vp1[x];
    };

    f32x4 z = {0.f, 0.f, 0.f, 0.f};
    f32x4 acc[2][4];
    float mrun[2][4], lpart[2][4];
#pragma unroll
    for (int m = 0; m < 2; m++) {
#pragma unroll
        for (int n = 0; n < 4; n++) acc[m][n] = z;
#pragma unroll
        for (int r = 0; r < 4; r++) { mrun[m][r] = -__builtin_inff(); lpart[m][r] = 0.f; }
    }

    int ntiles = ((q0 + 31) >> 6) + 1;
    STAGE_LOAD(0);
    STAGE_WRITE(0);

    for (int kt = 0; kt < ntiles; kt++) {
        int bu = kt & 1;
        int s0 = kt * 64;
        bool last = (kt == ntiles - 1);
        __syncthreads();
        if (!last) STAGE_LOAD(s0 + 64);     // issue next-tile HBM loads early (T14)

        // S = Q K^T over 64 keys
        short8 kf[4][2];
#pragma unroll
        for (int c = 0; c < 4; c++)
#pragma unroll
            for (int kk = 0; kk < 2; kk++)
                kf[c][kk] = *(const short8*)&Ks[bu][c * 16 + lr][kk * 32 + lg * 8];
        f32x4 sfr[2][4];
#pragma unroll
        for (int m = 0; m < 2; m++)
#pragma unroll
            for (int c = 0; c < 4; c++) {
                sfr[m][c] = z;
#pragma unroll
                for (int kk = 0; kk < 2; kk++)
                    sfr[m][c] = __builtin_amdgcn_mfma_f32_16x16x32_bf16(
                        qf[m][kk], kf[c][kk], sfr[m][c], 0, 0, 0);
            }

        // online softmax (exp2 domain; scores already scaled via Q)
#pragma unroll
        for (int m = 0; m < 2; m++) {
#pragma unroll
            for (int r = 0; r < 4; r++) {
                float v0 = sfr[m][0][r], v1 = sfr[m][1][r];
                float v2 = sfr[m][2][r], v3 = sfr[m][3][r];
                if (last) {
                    int qrow = q0 + m * 16 + lg * 4 + r;
                    if (s0 + lr      > qrow) v0 = -__builtin_inff();
                    if (s0 + 16 + lr > qrow) v1 = -__builtin_inff();
                    if (s0 + 32 + lr > qrow) v2 = -__builtin_inff();
                    if (s0 + 48 + lr > qrow) v3 = -__builtin_inff();
                }
                float mx = fmaxf(fmaxf(v0, v1), fmaxf(v2, v3));
#pragma unroll
                for (int sh = 1; sh < 16; sh <<= 1) mx = fmaxf(mx, __shfl_xor(mx, sh, 64));
                float mnew = fmaxf(mrun[m][r], mx);
                float p0 = exp2f(v0 - mnew);
                float p1 = exp2f(v1 - mnew);
                float p2 = exp2f(v2 - mnew);
                float p3 = exp2f(v3 - mnew);
                float alpha = exp2f(mrun[m][r] - mnew);
                mrun[m][r] = mnew;
                lpart[m][r] = lpart[m][r] * alpha + ((p0 + p1) + (p2 + p3));
#pragma unroll
                for (int n = 0; n < 4; n++) acc[m][n][r] *= alpha;
                unsigned pk01 = (unsigned)bf16r(p0) | ((unsigned)bf16r(p1) << 16);
                unsigned pk23 = (unsigned)bf16r(p2) | ((unsigned)bf16r(p3) << 16);
                unsigned* prow = (unsigned*)&Ps[w][m * 16 + lg * 4 + r][0];
                prow[lr]      = pk01;   // slots 2lr,2lr+1   = keys lr, 16+lr
                prow[16 + lr] = pk23;   // slots 32+2lr,+1   = keys 32+lr, 48+lr
            }
        }

        if (!last) STAGE_WRITE(bu ^ 1);     // HBM latency hidden under QK+softmax

        // O += P V (k-order = slot order on both operands)
        short8 pa[2][2], vb[4][2];
#pragma unroll
        for (int m = 0; m < 2; m++)
#pragma unroll
            for (int k2 = 0; k2 < 2; k2++)
                pa[m][k2] = *(const short8*)&Ps[w][m * 16 + lr][k2 * 32 + lg * 8];
#pragma unroll
        for (int n = 0; n < 4; n++)
#pragma unroll
            for (int k2 = 0; k2 < 2; k2++)
                vb[n][k2] = *(const short8*)&Vs[bu][n * 16 + lr][k2 * 32 + lg * 8];
#pragma unroll
        for (int m = 0; m < 2; m++)
#pragma unroll
            for (int n = 0; n < 4; n++)
#pragma unroll
                for (int k2 = 0; k2 < 2; k2++)
                    acc[m][n] = __builtin_amdgcn_mfma_f32_16x16x32_bf16(
                        pa[m][k2], vb[n][k2], acc[m][n], 0, 0, 0);
    }

    // final l reduce (deferred sum) + output
#pragma unroll
    for (int m = 0; m < 2; m++)
#pragma unroll
        for (int r = 0; r < 4; r++) {
            float ls = lpart[m][r];
#pragma unroll
            for (int sh = 1; sh < 16; sh <<= 1) ls += __shfl_xor(ls, sh, 64);
            float inv = 1.0f / ls;
            int row = q0 + m * 16 + lg * 4 + r;
#pragma unroll
            for (int n = 0; n < 4; n++) {
                int col = g * 256 + w * 64 + n * 16 + lr;
                attn[((size_t)b * T_ + row) * DOUT_ + col] =
                    (short)bf16r(acc[m][n][r] * inv);
            }
        }
}

extern "C" void kernel_launch(void* const* d_in, const int* in_sizes, int n_in,
                              void* d_out, int out_size, void* d_ws, size_t ws_size,
                              hipStream_t stream) {
    const float* x    = (const float*)d_in[0];
    const float* Wq   = (const float*)d_in[1];
    const float* Wk   = (const float*)d_in[2];
    const float* Wv   = (const float*)d_in[3];
    const float* Wo   = (const float*)d_in[4];
    const float* cosT = (const float*)d_in[5];
    const float* sinT = (const float*)d_in[6];

    char* ws = (char*)d_ws;
    short* WT  = (short*)(ws);              // [1536][1024] bf16 (WqT|WkT|WvT)
    short* WoT = (short*)(ws + 3145728);    // [1024][1024] bf16
    short* QKV = (short*)(ws + 5242880);    // [4096][1536] bf16
    short* ATT = (short*)(ws + 17825792);   // [4096][1024] bf16

    k_transpose<<<dim3(16, 16), 256, 0, stream>>>(Wq, WT, 1024, 1024);
    k_transpose<<<dim3(16, 4),  256, 0, stream>>>(Wk, WT + 1024 * 1024, 1024, 256);
    k_transpose<<<dim3(16, 4),  256, 0, stream>>>(Wv, WT + 1280 * 1024, 1024, 256);
    k_transpose<<<dim3(16, 16), 256, 0, stream>>>(Wo, WoT, 1024, 1024);

    k_gemm<float, 0><<<dim3(32, 12), 256, 0, stream>>>(x, WT, (void*)QKV, 4096, 1536, 1024);
    k_rope<<<4096, 640, 0, stream>>>(QKV, cosT, sinT);
    k_attn<<<512, 256, 0, stream>>>(QKV, ATT);
    k_gemm<short, 1><<<dim3(32, 8), 256, 0, stream>>>(ATT, WoT, d_out, 4096, 1024, 1024);
}

// Round 4
// 177.078 us; speedup vs baseline: 1.3798x; 1.0100x over previous
//
#include <hip/hip_runtime.h>
#include <hip/hip_bf16.h>

typedef __attribute__((ext_vector_type(8))) short short8;
typedef __attribute__((ext_vector_type(4))) float f32x4;

#define T_    2048
#define QKVN  1536
#define DOUT_ 1024

__device__ __forceinline__ unsigned short bf16r(float f) {
    union { float f; unsigned u; } v; v.f = f;
    unsigned r = v.u + 0x7fffu + ((v.u >> 16) & 1u);   // round-to-nearest-even
    return (unsigned short)(r >> 16);
}
__device__ __forceinline__ float fbf16(short s) {
    union { unsigned u; float f; } v; v.u = ((unsigned)(unsigned short)s) << 16;
    return v.f;
}

// src [K][N] f32  ->  dst [N][K] bf16, LDS-tiled 64x64
__global__ __launch_bounds__(256)
void k_transpose(const float* __restrict__ src, short* __restrict__ dst,
                 int K, int N) {
    __shared__ short tile[64][72];
    int tk = blockIdx.x * 64;
    int tn = blockIdx.y * 64;
    int t = threadIdx.x;
    int r4 = t >> 6, c = t & 63;
#pragma unroll
    for (int i = 0; i < 16; i++) {
        int row = i * 4 + r4;
        tile[c][row] = (short)bf16r(src[(size_t)(tk + row) * N + tn + c]);
    }
    __syncthreads();
    int row = t >> 2, seg = t & 3;
    short8 a = *(const short8*)&tile[row][seg * 16];
    short8 b = *(const short8*)&tile[row][seg * 16 + 8];
    *(short8*)&dst[(size_t)(tn + row) * K + tk + seg * 16]     = a;
    *(short8*)&dst[(size_t)(tn + row) * K + tk + seg * 16 + 8] = b;
}

// in-place RoPE on Q (16 heads) and K (4 heads) columns of QKV [4096][1536]
__global__ void k_rope(short* __restrict__ qkv, const float* __restrict__ cosT,
                       const float* __restrict__ sinT) {
    int row = blockIdx.x;
    int t   = row & (T_ - 1);
    int h   = threadIdx.x >> 5;        // 0..19
    int d   = threadIdx.x & 31;
    int base = (h < 16) ? (h * 64) : (1024 + (h - 16) * 64);
    float cd = cosT[t * 64 + d];
    float sd = sinT[t * 64 + d];
    short* p = qkv + (size_t)row * QKVN + base;
    float a = fbf16(p[d]);
    float b = fbf16(p[d + 32]);
    p[d]      = (short)bf16r(a * cd - b * sd);
    p[d + 32] = (short)bf16r(b * cd + a * sd);
}

// V region of QKV -> VT [b][g][d=64][2048 keys, slot-permuted within 64-blocks]
__global__ __launch_bounds__(256)
void k_vt(const short* __restrict__ qkv, short* __restrict__ vt) {
    __shared__ short tile[64][72];
    int bid = blockIdx.x;
    int b = bid & 1, g = (bid >> 1) & 3, tt = bid >> 3;
    int t0 = tt * 64;
    int tid = threadIdx.x;
    int row = tid >> 2, sp = tid & 3;   // row = local key, sp = 16-d segment
    const short* src = qkv + ((size_t)(b * T_ + t0 + row) * QKVN + 1280 + g * 64 + sp * 16);
    uint4 a = *(const uint4*)src;
    uint4 c = *(const uint4*)(src + 8);
    // slot permutation: keys (i,16+i)->(2i,2i+1) within each 32-half
    int slot = (row & 32) + ((row & 15) << 1) + ((row >> 4) & 1);
    const short* ap = (const short*)&a;
    const short* cp = (const short*)&c;
#pragma unroll
    for (int x = 0; x < 8; x++) tile[sp * 16 + x][slot]     = ap[x];
#pragma unroll
    for (int x = 0; x < 8; x++) tile[sp * 16 + 8 + x][slot] = cp[x];
    __syncthreads();
    int d = tid >> 2;
    short* dst = vt + ((size_t)((b * 4 + g) * 64 + d) * T_ + t0 + sp * 16);
    *(uint4*)dst       = *(const uint4*)&tile[d][sp * 16];
    *(uint4*)(dst + 8) = *(const uint4*)&tile[d][sp * 16 + 8];
}

// C[M][N] = A[M][K] * Bt[N][K]^T (unchanged)
template <typename AT, int CF32>
__global__ __launch_bounds__(256)
void k_gemm(const AT* __restrict__ A, const short* __restrict__ Bt,
            void* __restrict__ Cv, int M, int N, int K) {
    __shared__ __align__(16) short As[128][72];
    __shared__ __align__(16) short Bs[128][72];
    int tid = threadIdx.x;
    int l = tid & 63, w = tid >> 6;
    int lr = l & 15, lg = l >> 4;
    int m0 = blockIdx.x * 128;
    int n0 = blockIdx.y * 128;
    int wr = (w >> 1) * 64, wc = (w & 1) * 64;

    f32x4 z = {0.f, 0.f, 0.f, 0.f};
    f32x4 acc[4][4];
#pragma unroll
    for (int m = 0; m < 4; m++)
#pragma unroll
        for (int n = 0; n < 4; n++) acc[m][n] = z;

    for (int k0 = 0; k0 < K; k0 += 64) {
#pragma unroll
        for (int c = tid; c < 1024; c += 256) {
            int row = c >> 3, seg = c & 7;
            uint4 aval;
            if constexpr (sizeof(AT) == 4) {
                const float* s = (const float*)A + (size_t)(m0 + row) * K + k0 + seg * 8;
                float4 f1 = *(const float4*)s;
                float4 f2 = *(const float4*)(s + 4);
                aval.x = (unsigned)bf16r(f1.x) | ((unsigned)bf16r(f1.y) << 16);
                aval.y = (unsigned)bf16r(f1.z) | ((unsigned)bf16r(f1.w) << 16);
                aval.z = (unsigned)bf16r(f2.x) | ((unsigned)bf16r(f2.y) << 16);
                aval.w = (unsigned)bf16r(f2.z) | ((unsigned)bf16r(f2.w) << 16);
            } else {
                aval = *(const uint4*)((const short*)A + (size_t)(m0 + row) * K + k0 + seg * 8);
            }
            *(uint4*)&As[row][seg * 8] = aval;
            *(uint4*)&Bs[row][seg * 8] =
                *(const uint4*)(Bt + (size_t)(n0 + row) * K + k0 + seg * 8);
        }
        __syncthreads();
#pragma unroll
        for (int kk = 0; kk < 2; kk++) {
            short8 af[4], bf[4];
#pragma unroll
            for (int m = 0; m < 4; m++)
                af[m] = *(const short8*)&As[wr + m * 16 + lr][kk * 32 + lg * 8];
#pragma unroll
            for (int n = 0; n < 4; n++)
                bf[n] = *(const short8*)&Bs[wc + n * 16 + lr][kk * 32 + lg * 8];
#pragma unroll
            for (int m = 0; m < 4; m++)
#pragma unroll
                for (int n = 0; n < 4; n++)
                    acc[m][n] = __builtin_amdgcn_mfma_f32_16x16x32_bf16(
                        af[m], bf[n], acc[m][n], 0, 0, 0);
        }
        __syncthreads();
    }
#pragma unroll
    for (int m = 0; m < 4; m++)
#pragma unroll
        for (int n = 0; n < 4; n++)
#pragma unroll
            for (int r = 0; r < 4; r++) {
                int row = m0 + wr + m * 16 + lg * 4 + r;
                int col = n0 + wc + n * 16 + lr;
                float v = acc[m][n][r];
                if (CF32) ((float*)Cv)[(size_t)row * N + col] = v;
                else      ((short*)Cv)[(size_t)row * N + col] = (short)bf16r(v);
            }
}

// Flash attention v3: m=0 softmax (exact; scores tiny due to 1/sqrt(T) scale),
// single-buffer K/V (36.9KB LDS -> 4 blocks/CU), VT-pretransposed V,
// split-K (qt>=32 in 2 chunks) with linear f32 partial combine.
__global__ __launch_bounds__(256, 4)
void k_attn(const short* __restrict__ qkv, const short* __restrict__ vt,
            short* __restrict__ attn, float* __restrict__ opart,
            float* __restrict__ lpart, int split) {
    __shared__ __align__(16) short Ks[64][72];
    __shared__ __align__(16) short Vs[64][72];    // Vs[d][slot]
    __shared__ __align__(16) short Ps[4][32][72]; // Ps[wave][q][slot]
    int id = blockIdx.x;
    int mode, bg, qt, c = 0;
    if (split) {
        if (id < 512) { mode = 1; c = id & 1; bg = (id >> 1) & 7; qt = 63 - (id >> 4); }
        else          { mode = 0; int i2 = id - 512; bg = i2 & 7; qt = 31 - (i2 >> 3); }
    } else { mode = 0; bg = id & 7; qt = 63 - (id >> 3); }
    int b = bg & 1, g = (bg >> 1) & 3;
    int q0 = qt * 32;
    int nt = (qt + 2) >> 1;               // total key-tiles for this qt
    int nt1 = nt >> 1;
    int t0 = 0, t1 = nt;
    if (mode == 1) { t0 = c ? nt1 : 0; t1 = c ? nt : nt1; }

    int tid = threadIdx.x;
    int w = tid >> 6;
    int l = tid & 63;
    int lr = l & 15, lg = l >> 4;
    const float s2 = 0.03187928f;         // log2(e)/sqrt(2048)
    size_t rowbase = (size_t)b * T_ * QKVN;
    int qcol = g * 256 + w * 64;
    int kcol = 1024 + g * 64;
    const short* vrow = vt + (size_t)((b * 4 + g) * 64) * T_;

    // Q fragments, pre-scaled by s2
    short8 qf[2][2];
#pragma unroll
    for (int m = 0; m < 2; m++)
#pragma unroll
        for (int kk = 0; kk < 2; kk++) {
            short8 raw = *(const short8*)(qkv + rowbase +
                          (size_t)(q0 + m * 16 + lr) * QKVN + qcol + kk * 32 + lg * 8);
            short8 sc;
#pragma unroll
            for (int x = 0; x < 8; x++) sc[x] = (short)bf16r(fbf16(raw[x]) * s2);
            qf[m][kk] = sc;
        }

    int srow = tid >> 2, sp = tid & 3;
    uint4 sK0, sK1, sV0, sV1;
    auto STAGE_LOAD = [&](int kt) {
        int s0 = kt * 64;
        const uint4* ks = (const uint4*)(qkv + rowbase + (size_t)(s0 + srow) * QKVN + kcol);
        sK0 = ks[sp * 2]; sK1 = ks[sp * 2 + 1];
        const short* vs = vrow + (size_t)srow * T_ + s0 + sp * 16;
        sV0 = *(const uint4*)vs; sV1 = *(const uint4*)(vs + 8);
    };
    auto STAGE_WRITE = [&]() {
        *(uint4*)&Ks[srow][sp * 16]     = sK0;
        *(uint4*)&Ks[srow][sp * 16 + 8] = sK1;
        *(uint4*)&Vs[srow][sp * 16]     = sV0;
        *(uint4*)&Vs[srow][sp * 16 + 8] = sV1;
    };

    f32x4 z = {0.f, 0.f, 0.f, 0.f};
    f32x4 acc[2][4];
    float lp[2][4];
#pragma unroll
    for (int m = 0; m < 2; m++) {
#pragma unroll
        for (int n = 0; n < 4; n++) acc[m][n] = z;
#pragma unroll
        for (int r = 0; r < 4; r++) lp[m][r] = 0.f;
    }

    STAGE_LOAD(t0);
    for (int kt = t0; kt < t1; kt++) {
        int s0 = kt * 64;
        bool last = (kt == nt - 1);       // diagonal tile (only in last chunk)
        STAGE_WRITE();
        __syncthreads();
        if (kt + 1 < t1) STAGE_LOAD(kt + 1);   // hide HBM under compute (T14)

        // S = Q K^T over 64 keys
        short8 kf[4][2];
#pragma unroll
        for (int cc = 0; cc < 4; cc++)
#pragma unroll
            for (int kk = 0; kk < 2; kk++)
                kf[cc][kk] = *(const short8*)&Ks[cc * 16 + lr][kk * 32 + lg * 8];
        f32x4 sfr[2][4];
#pragma unroll
        for (int m = 0; m < 2; m++)
#pragma unroll
            for (int cc = 0; cc < 4; cc++) {
                sfr[m][cc] = z;
#pragma unroll
                for (int kk = 0; kk < 2; kk++)
                    sfr[m][cc] = __builtin_amdgcn_mfma_f32_16x16x32_bf16(
                        qf[m][kk], kf[cc][kk], sfr[m][cc], 0, 0, 0);
            }

        // m=0 softmax: P = exp2(score); no max-reduce, no rescale
#pragma unroll
        for (int m = 0; m < 2; m++) {
#pragma unroll
            for (int r = 0; r < 4; r++) {
                float v0 = sfr[m][0][r], v1 = sfr[m][1][r];
                float v2 = sfr[m][2][r], v3 = sfr[m][3][r];
                if (last) {
                    int qrow = q0 + m * 16 + lg * 4 + r;
                    if (s0 + lr      > qrow) v0 = -__builtin_inff();
                    if (s0 + 16 + lr > qrow) v1 = -__builtin_inff();
                    if (s0 + 32 + lr > qrow) v2 = -__builtin_inff();
                    if (s0 + 48 + lr > qrow) v3 = -__builtin_inff();
                }
                float p0 = exp2f(v0), p1 = exp2f(v1);
                float p2 = exp2f(v2), p3 = exp2f(v3);
                lp[m][r] += (p0 + p1) + (p2 + p3);
                unsigned pk01 = (unsigned)bf16r(p0) | ((unsigned)bf16r(p1) << 16);
                unsigned pk23 = (unsigned)bf16r(p2) | ((unsigned)bf16r(p3) << 16);
                unsigned* prow = (unsigned*)&Ps[w][m * 16 + lg * 4 + r][0];
                prow[lr]      = pk01;   // slots 2lr,2lr+1 = keys lr,16+lr (matches VT perm)
                prow[16 + lr] = pk23;
            }
        }

        // O += P V
        short8 pa[2][2], vb[4][2];
#pragma unroll
        for (int m = 0; m < 2; m++)
#pragma unroll
            for (int k2 = 0; k2 < 2; k2++)
                pa[m][k2] = *(const short8*)&Ps[w][m * 16 + lr][k2 * 32 + lg * 8];
#pragma unroll
        for (int n = 0; n < 4; n++)
#pragma unroll
            for (int k2 = 0; k2 < 2; k2++)
                vb[n][k2] = *(const short8*)&Vs[n * 16 + lr][k2 * 32 + lg * 8];
#pragma unroll
        for (int m = 0; m < 2; m++)
#pragma unroll
            for (int n = 0; n < 4; n++)
#pragma unroll
                for (int k2 = 0; k2 < 2; k2++)
                    acc[m][n] = __builtin_amdgcn_mfma_f32_16x16x32_bf16(
                        pa[m][k2], vb[n][k2], acc[m][n], 0, 0, 0);
        __syncthreads();
    }

    // deferred l reduce (sum over 16 lr lanes; xor<16 stays within lg group)
    if (mode == 0) {
#pragma unroll
        for (int m = 0; m < 2; m++)
#pragma unroll
            for (int r = 0; r < 4; r++) {
                float ls = lp[m][r];
#pragma unroll
                for (int sh = 1; sh < 16; sh <<= 1) ls += __shfl_xor(ls, sh, 64);
                float inv = 1.0f / ls;
                int row = q0 + m * 16 + lg * 4 + r;
#pragma unroll
                for (int n = 0; n < 4; n++) {
                    int col = g * 256 + w * 64 + n * 16 + lr;
                    attn[((size_t)b * T_ + row) * DOUT_ + col] =
                        (short)bf16r(acc[m][n][r] * inv);
                }
            }
    } else {
        int oid = ((bg * 32 + (qt - 32)) * 2 + c);
        float* ob = opart + (size_t)oid * 8192;
#pragma unroll
        for (int m = 0; m < 2; m++)
#pragma unroll
            for (int r = 0; r < 4; r++) {
                float ls = lp[m][r];
#pragma unroll
                for (int sh = 1; sh < 16; sh <<= 1) ls += __shfl_xor(ls, sh, 64);
                int row = m * 16 + lg * 4 + r;
                if (lr == 0) lpart[oid * 128 + row * 4 + w] = ls;
#pragma unroll
                for (int n = 0; n < 4; n++) {
                    int col = w * 64 + n * 16 + lr;   // LOCAL col (bugfix: no g*256)
                    ob[row * 256 + col] = acc[m][n][r];
                }
            }
    }
}

// combine: out = (O0+O1) / (l0+l1) for qt>=32
__global__ __launch_bounds__(256)
void k_comb(const float* __restrict__ opart, const float* __restrict__ lpart,
            short* __restrict__ attn) {
    int id = blockIdx.x;
    int bg = id & 7, qtl = id >> 3;
    int qt = 32 + qtl;
    int b = bg & 1, g = (bg >> 1) & 3;
    int oid0 = (bg * 32 + qtl) * 2;
    int t = threadIdx.x;
    int row = t >> 3, s = t & 7;
    int head = s >> 1, colseg = s * 32;
    const float* O0 = opart + (size_t)oid0 * 8192 + row * 256 + colseg;
    const float* O1 = O0 + 8192;
    float lsum = lpart[oid0 * 128 + row * 4 + head] +
                 lpart[(oid0 + 1) * 128 + row * 4 + head];
    float inv = 1.0f / lsum;
    unsigned out[16];
#pragma unroll
    for (int i = 0; i < 8; i++) {
        float4 a = *(const float4*)(O0 + i * 4);
        float4 bb = *(const float4*)(O1 + i * 4);
        float e0 = (a.x + bb.x) * inv, e1 = (a.y + bb.y) * inv;
        float e2 = (a.z + bb.z) * inv, e3 = (a.w + bb.w) * inv;
        out[i * 2]     = (unsigned)bf16r(e0) | ((unsigned)bf16r(e1) << 16);
        out[i * 2 + 1] = (unsigned)bf16r(e2) | ((unsigned)bf16r(e3) << 16);
    }
    short* dst = attn + ((size_t)(b * T_ + qt * 32 + row)) * DOUT_ + g * 256 + colseg;
#pragma unroll
    for (int i = 0; i < 4; i++) *(uint4*)(dst + i * 8) = *(const uint4*)&out[i * 4];
}

extern "C" void kernel_launch(void* const* d_in, const int* in_sizes, int n_in,
                              void* d_out, int out_size, void* d_ws, size_t ws_size,
                              hipStream_t stream) {
    const float* x    = (const float*)d_in[0];
    const float* Wq   = (const float*)d_in[1];
    const float* Wk   = (const float*)d_in[2];
    const float* Wv   = (const float*)d_in[3];
    const float* Wo   = (const float*)d_in[4];
    const float* cosT = (const float*)d_in[5];
    const float* sinT = (const float*)d_in[6];

    char* ws = (char*)d_ws;
    short* WT    = (short*)(ws);             // [1536][1024] bf16
    short* WoT   = (short*)(ws + 3145728);   // [1024][1024] bf16
    short* QKV   = (short*)(ws + 5242880);   // [4096][1536] bf16
    short* ATT   = (short*)(ws + 17825792);  // [4096][1024] bf16
    short* VT    = (short*)(ws + 26214400);  // [8][64][2048] bf16 (slot-permuted)
    float* OPART = (float*)(ws + 28311552);  // [512][32][256] f32
    float* LPART = (float*)(ws + 45088768);  // [512][128] f32
    int split = (ws_size >= 45350912u) ? 1 : 0;

    k_transpose<<<dim3(16, 16), 256, 0, stream>>>(Wq, WT, 1024, 1024);
    k_transpose<<<dim3(16, 4),  256, 0, stream>>>(Wk, WT + 1024 * 1024, 1024, 256);
    k_transpose<<<dim3(16, 4),  256, 0, stream>>>(Wv, WT + 1280 * 1024, 1024, 256);
    k_transpose<<<dim3(16, 16), 256, 0, stream>>>(Wo, WoT, 1024, 1024);

    k_gemm<float, 0><<<dim3(32, 12), 256, 0, stream>>>(x, WT, (void*)QKV, 4096, 1536, 1024);
    k_rope<<<4096, 640, 0, stream>>>(QKV, cosT, sinT);
    k_vt<<<256, 256, 0, stream>>>(QKV, VT);
    k_attn<<<split ? 768 : 512, 256, 0, stream>>>(QKV, VT, ATT, OPART, LPART, split);
    if (split) k_comb<<<256, 256, 0, stream>>>(OPART, LPART, ATT);
    k_gemm<short, 1><<<dim3(32, 8), 256, 0, stream>>>(ATT, WoT, d_out, 4096, 1024, 1024);
}

// Round 5
// 151.673 us; speedup vs baseline: 1.6109x; 1.1675x over previous
//
#include <hip/hip_runtime.h>
#include <hip/hip_bf16.h>

typedef __attribute__((ext_vector_type(8))) short short8;
typedef __attribute__((ext_vector_type(4))) float f32x4;
typedef __attribute__((ext_vector_type(16))) float f32x16;

#define T_    2048
#define QKVN  1536
#define DOUT_ 1024

__device__ __forceinline__ unsigned short bf16r(float f) {
    union { float f; unsigned u; } v; v.f = f;
    unsigned r = v.u + 0x7fffu + ((v.u >> 16) & 1u);   // round-to-nearest-even
    return (unsigned short)(r >> 16);
}
__device__ __forceinline__ float fbf16(short s) {
    union { unsigned u; float f; } v; v.u = ((unsigned)(unsigned short)s) << 16;
    return v.f;
}
// v_permlane32_swap_b32: a' = {a.lo32lanes, b.lo32lanes-from-lanes<32? no:}
// semantics: swaps lanes32-63 of a with lanes0-31 of b (row1(a) <-> row0(b)).
__device__ __forceinline__ void plswap(unsigned &a, unsigned &b) {
    asm volatile("v_permlane32_swap_b32 %0, %1" : "+v"(a), "+v"(b));
}

// src [K][N] f32  ->  dst [N][K] bf16, LDS-tiled 64x64
__global__ __launch_bounds__(256)
void k_transpose(const float* __restrict__ src, short* __restrict__ dst,
                 int K, int N) {
    __shared__ short tile[64][72];
    int tk = blockIdx.x * 64;
    int tn = blockIdx.y * 64;
    int t = threadIdx.x;
    int r4 = t >> 6, c = t & 63;
#pragma unroll
    for (int i = 0; i < 16; i++) {
        int row = i * 4 + r4;
        tile[c][row] = (short)bf16r(src[(size_t)(tk + row) * N + tn + c]);
    }
    __syncthreads();
    int row = t >> 2, seg = t & 3;
    short8 a = *(const short8*)&tile[row][seg * 16];
    short8 b = *(const short8*)&tile[row][seg * 16 + 8];
    *(short8*)&dst[(size_t)(tn + row) * K + tk + seg * 16]     = a;
    *(short8*)&dst[(size_t)(tn + row) * K + tk + seg * 16 + 8] = b;
}

// V region of QKV -> VT [b][g][d=64][2048 keys] (identity key order)
__global__ __launch_bounds__(256)
void k_vt(const short* __restrict__ qkv, short* __restrict__ vt) {
    __shared__ short tile[64][72];
    int bid = blockIdx.x;
    int b = bid & 1, g = (bid >> 1) & 3, tt = bid >> 3;
    int t0v = tt * 64;
    int tid = threadIdx.x;
    int row = tid >> 2, sp = tid & 3;
    const short* src = qkv + ((size_t)(b * T_ + t0v + row) * QKVN + 1280 + g * 64 + sp * 16);
    uint4 a = *(const uint4*)src;
    uint4 c2 = *(const uint4*)(src + 8);
    const short* ap = (const short*)&a;
    const short* cp = (const short*)&c2;
#pragma unroll
    for (int x = 0; x < 8; x++) tile[sp * 16 + x][row]     = ap[x];
#pragma unroll
    for (int x = 0; x < 8; x++) tile[sp * 16 + 8 + x][row] = cp[x];
    __syncthreads();
    int d = tid >> 2;
    short* dst = vt + ((size_t)((b * 4 + g) * 64 + d) * T_ + t0v + sp * 16);
    *(uint4*)dst       = *(const uint4*)&tile[d][sp * 16];
    *(uint4*)(dst + 8) = *(const uint4*)&tile[d][sp * 16 + 8];
}

// C[M][N] = A[M][K] * Bt[N][K]^T ; ROPE=1 applies rotary in-register to cols<1280
template <typename AT, int CF32, int ROPE>
__global__ __launch_bounds__(256)
void k_gemm(const AT* __restrict__ A, const short* __restrict__ Bt,
            void* __restrict__ Cv, int M, int N, int K,
            const float* __restrict__ cosT, const float* __restrict__ sinT) {
    __shared__ __align__(16) short As[128][72];
    __shared__ __align__(16) short Bs[128][72];
    int tid = threadIdx.x;
    int l = tid & 63, w = tid >> 6;
    int lr = l & 15, lg = l >> 4;
    int m0 = blockIdx.x * 128;
    int n0 = blockIdx.y * 128;
    int wr = (w >> 1) * 64, wc = (w & 1) * 64;

    f32x4 z = {0.f, 0.f, 0.f, 0.f};
    f32x4 acc[4][4];
#pragma unroll
    for (int m = 0; m < 4; m++)
#pragma unroll
        for (int n = 0; n < 4; n++) acc[m][n] = z;

    for (int k0 = 0; k0 < K; k0 += 64) {
#pragma unroll
        for (int c = tid; c < 1024; c += 256) {
            int row = c >> 3, seg = c & 7;
            uint4 aval;
            if constexpr (sizeof(AT) == 4) {
                const float* s = (const float*)A + (size_t)(m0 + row) * K + k0 + seg * 8;
                float4 f1 = *(const float4*)s;
                float4 f2 = *(const float4*)(s + 4);
                aval.x = (unsigned)bf16r(f1.x) | ((unsigned)bf16r(f1.y) << 16);
                aval.y = (unsigned)bf16r(f1.z) | ((unsigned)bf16r(f1.w) << 16);
                aval.z = (unsigned)bf16r(f2.x) | ((unsigned)bf16r(f2.y) << 16);
                aval.w = (unsigned)bf16r(f2.z) | ((unsigned)bf16r(f2.w) << 16);
            } else {
                aval = *(const uint4*)((const short*)A + (size_t)(m0 + row) * K + k0 + seg * 8);
            }
            *(uint4*)&As[row][seg * 8] = aval;
            *(uint4*)&Bs[row][seg * 8] =
                *(const uint4*)(Bt + (size_t)(n0 + row) * K + k0 + seg * 8);
        }
        __syncthreads();
#pragma unroll
        for (int kk = 0; kk < 2; kk++) {
            short8 af[4], bf[4];
#pragma unroll
            for (int m = 0; m < 4; m++)
                af[m] = *(const short8*)&As[wr + m * 16 + lr][kk * 32 + lg * 8];
#pragma unroll
            for (int n = 0; n < 4; n++)
                bf[n] = *(const short8*)&Bs[wc + n * 16 + lr][kk * 32 + lg * 8];
#pragma unroll
            for (int m = 0; m < 4; m++)
#pragma unroll
                for (int n = 0; n < 4; n++)
                    acc[m][n] = __builtin_amdgcn_mfma_f32_16x16x32_bf16(
                        af[m], bf[n], acc[m][n], 0, 0, 0);
        }
        __syncthreads();
    }
#pragma unroll
    for (int m = 0; m < 4; m++)
#pragma unroll
        for (int r = 0; r < 4; r++) {
            int row = m0 + wr + m * 16 + lg * 4 + r;
            if (ROPE) {
                int h = (n0 + wc) >> 6;       // 64-col head block (wave-uniform)
                if (h < 20) {                 // Q heads 0..15, K heads 16..19
                    int t = row & (T_ - 1);
#pragma unroll
                    for (int n = 0; n < 2; n++) {
                        int d = n * 16 + lr;  // 0..31
                        float cd = cosT[t * 64 + d];
                        float sd = sinT[t * 64 + d];
                        float a = acc[m][n][r], bb = acc[m][n + 2][r];
                        acc[m][n][r]     = a * cd - bb * sd;
                        acc[m][n + 2][r] = bb * cd + a * sd;
                    }
                }
            }
#pragma unroll
            for (int n = 0; n < 4; n++) {
                int col = n0 + wc + n * 16 + lr;
                float v = acc[m][n][r];
                if (CF32) ((float*)Cv)[(size_t)row * N + col] = v;
                else      ((short*)Cv)[(size_t)row * N + col] = (short)bf16r(v);
            }
        }
}

// Flash attention v4: swapped-operand 32x32x16 MFMA, in-register P (no P LDS),
// m=0 softmax (exact at 1/sqrt(T) scale), permlane32_swap P redistribution,
// dbuf K/V 1 barrier/tile, split-K topology identical to R4.
__global__ __launch_bounds__(256, 3)
void k_attn(const short* __restrict__ qkv, const short* __restrict__ vt,
            short* __restrict__ attn, float* __restrict__ opart,
            float* __restrict__ lpart, int split) {
    __shared__ __align__(16) short Ks[2][64][72];   // [buf][key][d]
    __shared__ __align__(16) short Vs[2][64][72];   // [buf][d][key]
    int id = blockIdx.x;
    int mode, bg, qt, c = 0;
    if (split) {
        if (id < 512) { mode = 1; c = id & 1; bg = (id >> 1) & 7; qt = 63 - (id >> 4); }
        else          { mode = 0; int i2 = id - 512; bg = i2 & 7; qt = 31 - (i2 >> 3); }
    } else { mode = 0; bg = id & 7; qt = 63 - (id >> 3); }
    int b = bg & 1, g = (bg >> 1) & 3;
    int q0 = qt * 32;
    int nt = (qt + 2) >> 1;
    int nt1 = nt >> 1;
    int t0 = 0, t1 = nt;
    if (mode == 1) { t0 = c ? nt1 : 0; t1 = c ? nt : nt1; }

    int tid = threadIdx.x;
    int w = tid >> 6;                 // head-in-group
    int l = tid & 63;
    int lc = l & 31, hi = l >> 5;
    const float s2 = 0.03187928f;     // log2(e)/sqrt(2048)
    size_t rowbase = (size_t)b * T_ * QKVN;
    int qcol = g * 256 + w * 64;
    int kcol = 1024 + g * 64;
    const short* vbase = vt + (size_t)((b * 4 + g) * 64) * T_;

    // Q as B-fragments: lane (lc,hi): Q[q0+lc][dkk*16 + hi*8 + j], prescaled by s2
    short8 qf[4];
#pragma unroll
    for (int dkk = 0; dkk < 4; dkk++) {
        short8 raw = *(const short8*)(qkv + rowbase + (size_t)(q0 + lc) * QKVN
                                      + qcol + dkk * 16 + hi * 8);
        short8 sc;
#pragma unroll
        for (int x = 0; x < 8; x++) sc[x] = (short)bf16r(fbf16(raw[x]) * s2);
        qf[dkk] = sc;
    }

    int srow = tid >> 2, sseg = tid & 3;     // staging: 4 threads/row, 32B each
    uint4 sK0, sK1, sV0, sV1;
    auto STAGE_LOAD = [&](int kt) {
        int s0 = kt * 64;
        const short* kp = qkv + rowbase + (size_t)(s0 + srow) * QKVN + kcol + sseg * 16;
        sK0 = *(const uint4*)kp; sK1 = *(const uint4*)(kp + 8);
        const short* vp = vbase + (size_t)srow * T_ + s0 + sseg * 16;   // srow = d
        sV0 = *(const uint4*)vp; sV1 = *(const uint4*)(vp + 8);
    };
    auto STAGE_WRITE = [&](int bu) {
        *(uint4*)&Ks[bu][srow][sseg * 16]     = sK0;
        *(uint4*)&Ks[bu][srow][sseg * 16 + 8] = sK1;
        *(uint4*)&Vs[bu][srow][sseg * 16]     = sV0;
        *(uint4*)&Vs[bu][srow][sseg * 16 + 8] = sV1;
    };

    f32x16 Z16 = {0.f,0.f,0.f,0.f,0.f,0.f,0.f,0.f,0.f,0.f,0.f,0.f,0.f,0.f,0.f,0.f};
    f32x16 acc[2];
    acc[0] = Z16; acc[1] = Z16;
    float lp = 0.f;

    STAGE_LOAD(t0);
    STAGE_WRITE(t0 & 1);

    for (int kt = t0; kt < t1; kt++) {
        int bu = kt & 1;
        int s0 = kt * 64;
        bool last = (kt == nt - 1);
        __syncthreads();                       // buf[bu] ready; prev compute done
        if (kt + 1 < t1) STAGE_LOAD(kt + 1);   // issue next-tile loads (hide HBM)

#pragma unroll
        for (int kf = 0; kf < 2; kf++) {
            // S^T[key][q] block: A=K (rows=keys kf*32+lc, k=d), B=Q
            f32x16 s = Z16;
#pragma unroll
            for (int dkk = 0; dkk < 4; dkk++) {
                short8 ka = *(const short8*)&Ks[bu][kf * 32 + lc][dkk * 16 + hi * 8];
                s = __builtin_amdgcn_mfma_f32_32x32x16_bf16(ka, qf[dkk], s, 0, 0, 0);
            }
            // lane holds P[key=kb+(r)+(8s)][q=q0+lc]; m=0 softmax: p=exp2(score)
            float p[16];
            if (last) {
                int qrow = q0 + lc;
                int kb = s0 + kf * 32 + hi * 4;
#pragma unroll
                for (int reg = 0; reg < 16; reg++) {
                    int key = kb + (reg & 3) + ((reg >> 2) << 3);
                    p[reg] = (key <= qrow) ? exp2f(s[reg]) : 0.f;
                }
            } else {
#pragma unroll
                for (int reg = 0; reg < 16; reg++) p[reg] = exp2f(s[reg]);
            }
#pragma unroll
            for (int reg = 0; reg < 16; reg++) lp += p[reg];
            // pack pairs (keys +0,+1) and (+2,+3) per 8-key sub-block
            unsigned pk[4][2];
#pragma unroll
            for (int sb = 0; sb < 4; sb++) {
                pk[sb][0] = (unsigned)bf16r(p[4 * sb])     | ((unsigned)bf16r(p[4 * sb + 1]) << 16);
                pk[sb][1] = (unsigned)bf16r(p[4 * sb + 2]) | ((unsigned)bf16r(p[4 * sb + 3]) << 16);
            }
#pragma unroll
            for (int kk = 0; kk < 2; kk++) {
                // redistribute: consumer lane needs keys (kf*32+kk*16+hi*8)+0..7
                unsigned a0 = pk[2 * kk][0], b0 = pk[2 * kk + 1][0];
                unsigned a1 = pk[2 * kk][1], b1 = pk[2 * kk + 1][1];
                plswap(a0, b0);
                plswap(a1, b1);
                union { unsigned u[4]; short8 s8; } pb;
                pb.u[0] = a0; pb.u[1] = a1; pb.u[2] = b0; pb.u[3] = b1;
#pragma unroll
                for (int df = 0; df < 2; df++) {
                    short8 va = *(const short8*)&Vs[bu][df * 32 + lc][kf * 32 + kk * 16 + hi * 8];
                    acc[df] = __builtin_amdgcn_mfma_f32_32x32x16_bf16(va, pb.s8, acc[df], 0, 0, 0);
                }
            }
        }
        if (kt + 1 < t1) STAGE_WRITE(bu ^ 1);  // write-late: after compute of bu
    }

    // l total per q-row: own hi-half + other hi-half
    float lt = lp + __shfl_xor(lp, 32, 64);

    if (mode == 0) {
        float inv = 1.0f / lt;
        short* obase = attn + ((size_t)b * T_ + q0 + lc) * DOUT_ + g * 256 + w * 64;
#pragma unroll
        for (int df = 0; df < 2; df++)
#pragma unroll
            for (int sb = 0; sb < 4; sb++) {
                unsigned u0 = (unsigned)bf16r(acc[df][4 * sb] * inv) |
                              ((unsigned)bf16r(acc[df][4 * sb + 1] * inv) << 16);
                unsigned u1 = (unsigned)bf16r(acc[df][4 * sb + 2] * inv) |
                              ((unsigned)bf16r(acc[df][4 * sb + 3] * inv) << 16);
                uint2 uv = {u0, u1};
                *(uint2*)(obase + df * 32 + sb * 8 + hi * 4) = uv;
            }
    } else {
        int oid = (bg * 32 + (qt - 32)) * 2 + c;
        float* ob = opart + (size_t)oid * 8192 + lc * 256 + w * 64;
#pragma unroll
        for (int df = 0; df < 2; df++)
#pragma unroll
            for (int sb = 0; sb < 4; sb++) {
                f32x4 vv = {acc[df][4 * sb], acc[df][4 * sb + 1],
                            acc[df][4 * sb + 2], acc[df][4 * sb + 3]};
                *(f32x4*)(ob + df * 32 + sb * 8 + hi * 4) = vv;
            }
        if (hi == 0) lpart[oid * 128 + lc * 4 + w] = lt;
    }
}

// combine: out = (O0+O1) / (l0+l1) for qt>=32
__global__ __launch_bounds__(256)
void k_comb(const float* __restrict__ opart, const float* __restrict__ lpart,
            short* __restrict__ attn) {
    int id = blockIdx.x;
    int bg = id & 7, qtl = id >> 3;
    int qt = 32 + qtl;
    int b = bg & 1, g = (bg >> 1) & 3;
    int oid0 = (bg * 32 + qtl) * 2;
    int t = threadIdx.x;
    int row = t >> 3, s = t & 7;
    int head = s >> 1, colseg = s * 32;
    const float* O0 = opart + (size_t)oid0 * 8192 + row * 256 + colseg;
    const float* O1 = O0 + 8192;
    float lsum = lpart[oid0 * 128 + row * 4 + head] +
                 lpart[(oid0 + 1) * 128 + row * 4 + head];
    float inv = 1.0f / lsum;
    unsigned out[16];
#pragma unroll
    for (int i = 0; i < 8; i++) {
        float4 a = *(const float4*)(O0 + i * 4);
        float4 bb = *(const float4*)(O1 + i * 4);
        float e0 = (a.x + bb.x) * inv, e1 = (a.y + bb.y) * inv;
        float e2 = (a.z + bb.z) * inv, e3 = (a.w + bb.w) * inv;
        out[i * 2]     = (unsigned)bf16r(e0) | ((unsigned)bf16r(e1) << 16);
        out[i * 2 + 1] = (unsigned)bf16r(e2) | ((unsigned)bf16r(e3) << 16);
    }
    short* dst = attn + ((size_t)(b * T_ + qt * 32 + row)) * DOUT_ + g * 256 + colseg;
#pragma unroll
    for (int i = 0; i < 4; i++) *(uint4*)(dst + i * 8) = *(const uint4*)&out[i * 4];
}

extern "C" void kernel_launch(void* const* d_in, const int* in_sizes, int n_in,
                              void* d_out, int out_size, void* d_ws, size_t ws_size,
                              hipStream_t stream) {
    const float* x    = (const float*)d_in[0];
    const float* Wq   = (const float*)d_in[1];
    const float* Wk   = (const float*)d_in[2];
    const float* Wv   = (const float*)d_in[3];
    const float* Wo   = (const float*)d_in[4];
    const float* cosT = (const float*)d_in[5];
    const float* sinT = (const float*)d_in[6];

    char* ws = (char*)d_ws;
    short* WT    = (short*)(ws);             // [1536][1024] bf16
    short* WoT   = (short*)(ws + 3145728);   // [1024][1024] bf16
    short* QKV   = (short*)(ws + 5242880);   // [4096][1536] bf16
    short* ATT   = (short*)(ws + 17825792);  // [4096][1024] bf16
    short* VT    = (short*)(ws + 26214400);  // [8][64][2048] bf16
    float* OPART = (float*)(ws + 28311552);  // [512][32][256] f32
    float* LPART = (float*)(ws + 45088768);  // [512][128] f32
    int split = (ws_size >= 45350912u) ? 1 : 0;

    k_transpose<<<dim3(16, 16), 256, 0, stream>>>(Wq, WT, 1024, 1024);
    k_transpose<<<dim3(16, 4),  256, 0, stream>>>(Wk, WT + 1024 * 1024, 1024, 256);
    k_transpose<<<dim3(16, 4),  256, 0, stream>>>(Wv, WT + 1280 * 1024, 1024, 256);
    k_transpose<<<dim3(16, 16), 256, 0, stream>>>(Wo, WoT, 1024, 1024);

    k_gemm<float, 0, 1><<<dim3(32, 12), 256, 0, stream>>>(x, WT, (void*)QKV,
                                                          4096, 1536, 1024, cosT, sinT);
    k_vt<<<256, 256, 0, stream>>>(QKV, VT);
    k_attn<<<split ? 768 : 512, 256, 0, stream>>>(QKV, VT, ATT, OPART, LPART, split);
    if (split) k_comb<<<256, 256, 0, stream>>>(OPART, LPART, ATT);
    k_gemm<short, 1, 0><<<dim3(32, 8), 256, 0, stream>>>(ATT, WoT, d_out,
                                                         4096, 1024, 1024, nullptr, nullptr);
}

// Round 6
// 121.732 us; speedup vs baseline: 2.0071x; 1.2460x over previous
//
#include <hip/hip_runtime.h>
#include <hip/hip_bf16.h>

typedef __attribute__((ext_vector_type(8))) short short8;
typedef __attribute__((ext_vector_type(4))) float f32x4;
typedef __attribute__((ext_vector_type(16))) float f32x16;

#define T_    2048
#define QKVN  1536
#define DOUT_ 1024

__device__ __forceinline__ unsigned short bf16r(float f) {
    union { float f; unsigned u; } v; v.f = f;
    unsigned r = v.u + 0x7fffu + ((v.u >> 16) & 1u);   // round-to-nearest-even
    return (unsigned short)(r >> 16);
}
__device__ __forceinline__ float fbf16(short s) {
    union { unsigned u; float f; } v; v.u = ((unsigned)(unsigned short)s) << 16;
    return v.f;
}
__device__ __forceinline__ void plswap(unsigned &a, unsigned &b) {
    asm volatile("v_permlane32_swap_b32 %0, %1" : "+v"(a), "+v"(b));
}
// async global->LDS, 16B per lane; LDS dest = wave-uniform base + lane*16
__device__ __forceinline__ void gload_lds16(const void* g, void* l) {
    __builtin_amdgcn_global_load_lds(
        (const __attribute__((address_space(1))) void*)g,
        (__attribute__((address_space(3))) void*)l, 16, 0, 0);
}

// x f32 -> bf16, 8 elems/thread
__global__ __launch_bounds__(256)
void k_xbf(const float* __restrict__ src, short* __restrict__ dst, int n8) {
    int i = blockIdx.x * blockDim.x + threadIdx.x;
    if (i >= n8) return;
    const float* s = src + (size_t)i * 8;
    float4 f1 = *(const float4*)s;
    float4 f2 = *(const float4*)(s + 4);
    uint4 o;
    o.x = (unsigned)bf16r(f1.x) | ((unsigned)bf16r(f1.y) << 16);
    o.y = (unsigned)bf16r(f1.z) | ((unsigned)bf16r(f1.w) << 16);
    o.z = (unsigned)bf16r(f2.x) | ((unsigned)bf16r(f2.y) << 16);
    o.w = (unsigned)bf16r(f2.z) | ((unsigned)bf16r(f2.w) << 16);
    *(uint4*)(dst + (size_t)i * 8) = o;
}

// src [K][N] f32  ->  dst [N][K] bf16, LDS-tiled 64x64
__global__ __launch_bounds__(256)
void k_transpose(const float* __restrict__ src, short* __restrict__ dst,
                 int K, int N) {
    __shared__ short tile[64][72];
    int tk = blockIdx.x * 64;
    int tn = blockIdx.y * 64;
    int t = threadIdx.x;
    int r4 = t >> 6, c = t & 63;
#pragma unroll
    for (int i = 0; i < 16; i++) {
        int row = i * 4 + r4;
        tile[c][row] = (short)bf16r(src[(size_t)(tk + row) * N + tn + c]);
    }
    __syncthreads();
    int row = t >> 2, seg = t & 3;
    short8 a = *(const short8*)&tile[row][seg * 16];
    short8 b = *(const short8*)&tile[row][seg * 16 + 8];
    *(short8*)&dst[(size_t)(tn + row) * K + tk + seg * 16]     = a;
    *(short8*)&dst[(size_t)(tn + row) * K + tk + seg * 16 + 8] = b;
}

// V region of QKV -> VT [b][g][d=64][2048 keys]
__global__ __launch_bounds__(256)
void k_vt(const short* __restrict__ qkv, short* __restrict__ vt) {
    __shared__ short tile[64][72];
    int bid = blockIdx.x;
    int b = bid & 1, g = (bid >> 1) & 3, tt = bid >> 3;
    int t0v = tt * 64;
    int tid = threadIdx.x;
    int row = tid >> 2, sp = tid & 3;
    const short* src = qkv + ((size_t)(b * T_ + t0v + row) * QKVN + 1280 + g * 64 + sp * 16);
    uint4 a = *(const uint4*)src;
    uint4 c2 = *(const uint4*)(src + 8);
    const short* ap = (const short*)&a;
    const short* cp = (const short*)&c2;
#pragma unroll
    for (int x = 0; x < 8; x++) tile[sp * 16 + x][row]     = ap[x];
#pragma unroll
    for (int x = 0; x < 8; x++) tile[sp * 16 + 8 + x][row] = cp[x];
    __syncthreads();
    int d = tid >> 2;
    short* dst = vt + ((size_t)((b * 4 + g) * 64 + d) * T_ + t0v + sp * 16);
    *(uint4*)dst       = *(const uint4*)&tile[d][sp * 16];
    *(uint4*)(dst + 8) = *(const uint4*)&tile[d][sp * 16 + 8];
}

// C[M][N] = A[M][K] * Bt[N][K]^T, A/Bt bf16. Tile 64(M)x128(N), BK=64,
// global_load_lds staging (m97 recipe), 4 waves 2x2, wave tile 32x64.
template <int CF32, int ROPE>
__global__ __launch_bounds__(256, 4)
void k_gemm(const short* __restrict__ A, const short* __restrict__ Bt,
            void* __restrict__ Cv, int M, int N, int K,
            const float* __restrict__ cosT, const float* __restrict__ sinT) {
    __shared__ __align__(16) short As[64][64];     // linear (gload_lds dest)
    __shared__ __align__(16) short Bs[128][64];
    int tid = threadIdx.x;
    int l = tid & 63, w = tid >> 6;
    int lr = l & 15, lg = l >> 4;
    int m0 = blockIdx.x * 64;
    int n0 = blockIdx.y * 128;
    int wr = (w >> 1) * 32, wc = (w & 1) * 64;
    int lrow = l >> 3, lcol = (l & 7) * 8;         // staging lane map

    f32x4 z = {0.f, 0.f, 0.f, 0.f};
    f32x4 acc[2][4];
#pragma unroll
    for (int m = 0; m < 2; m++)
#pragma unroll
        for (int n = 0; n < 4; n++) acc[m][n] = z;

    for (int k0 = 0; k0 < K; k0 += 64) {
        // stage A (8 chunks) + B (16 chunks), 1KB per gload_lds instr
#pragma unroll
        for (int i = 0; i < 2; i++) {
            int ch = w * 2 + i;
            gload_lds16(A + (size_t)(m0 + ch * 8 + lrow) * K + k0 + lcol,
                        &As[ch * 8][0]);
        }
#pragma unroll
        for (int i = 0; i < 4; i++) {
            int ch = w * 4 + i;
            gload_lds16(Bt + (size_t)(n0 + ch * 8 + lrow) * K + k0 + lcol,
                        &Bs[ch * 8][0]);
        }
        __syncthreads();   // drains vmcnt -> tiles ready
#pragma unroll
        for (int kk = 0; kk < 2; kk++) {
            short8 af[2], bf[4];
#pragma unroll
            for (int m = 0; m < 2; m++)
                af[m] = *(const short8*)&As[wr + m * 16 + lr][kk * 32 + lg * 8];
#pragma unroll
            for (int n = 0; n < 4; n++)
                bf[n] = *(const short8*)&Bs[wc + n * 16 + lr][kk * 32 + lg * 8];
#pragma unroll
            for (int m = 0; m < 2; m++)
#pragma unroll
                for (int n = 0; n < 4; n++)
                    acc[m][n] = __builtin_amdgcn_mfma_f32_16x16x32_bf16(
                        af[m], bf[n], acc[m][n], 0, 0, 0);
        }
        __syncthreads();   // done reading before next stage overwrites
    }
#pragma unroll
    for (int m = 0; m < 2; m++)
#pragma unroll
        for (int r = 0; r < 4; r++) {
            int row = m0 + wr + m * 16 + lg * 4 + r;
            if (ROPE) {
                int h = (n0 + wc) >> 6;        // 64-col head block (wave-uniform)
                if (h < 20) {                  // Q heads 0..15, K heads 16..19
                    int t = row & (T_ - 1);
#pragma unroll
                    for (int n = 0; n < 2; n++) {
                        int d = n * 16 + lr;   // 0..31
                        float cd = cosT[t * 64 + d];
                        float sd = sinT[t * 64 + d];
                        float a = acc[m][n][r], bb = acc[m][n + 2][r];
                        acc[m][n][r]     = a * cd - bb * sd;
                        acc[m][n + 2][r] = bb * cd + a * sd;
                    }
                }
            }
#pragma unroll
            for (int n = 0; n < 4; n++) {
                int col = n0 + wc + n * 16 + lr;
                float v = acc[m][n][r];
                if (CF32) ((float*)Cv)[(size_t)row * N + col] = v;
                else      ((short*)Cv)[(size_t)row * N + col] = (short)bf16r(v);
            }
        }
}

// Flash attention v4 (unchanged from R5): swapped-operand 32x32x16 MFMA,
// in-register P, m=0 softmax, permlane32_swap, dbuf K/V, split-K.
__global__ __launch_bounds__(256, 3)
void k_attn(const short* __restrict__ qkv, const short* __restrict__ vt,
            short* __restrict__ attn, float* __restrict__ opart,
            float* __restrict__ lpart, int split) {
    __shared__ __align__(16) short Ks[2][64][72];   // [buf][key][d]
    __shared__ __align__(16) short Vs[2][64][72];   // [buf][d][key]
    int id = blockIdx.x;
    int mode, bg, qt, c = 0;
    if (split) {
        if (id < 512) { mode = 1; c = id & 1; bg = (id >> 1) & 7; qt = 63 - (id >> 4); }
        else          { mode = 0; int i2 = id - 512; bg = i2 & 7; qt = 31 - (i2 >> 3); }
    } else { mode = 0; bg = id & 7; qt = 63 - (id >> 3); }
    int b = bg & 1, g = (bg >> 1) & 3;
    int q0 = qt * 32;
    int nt = (qt + 2) >> 1;
    int nt1 = nt >> 1;
    int t0 = 0, t1 = nt;
    if (mode == 1) { t0 = c ? nt1 : 0; t1 = c ? nt : nt1; }

    int tid = threadIdx.x;
    int w = tid >> 6;
    int l = tid & 63;
    int lc = l & 31, hi = l >> 5;
    const float s2 = 0.03187928f;     // log2(e)/sqrt(2048)
    size_t rowbase = (size_t)b * T_ * QKVN;
    int qcol = g * 256 + w * 64;
    int kcol = 1024 + g * 64;
    const short* vbase = vt + (size_t)((b * 4 + g) * 64) * T_;

    short8 qf[4];
#pragma unroll
    for (int dkk = 0; dkk < 4; dkk++) {
        short8 raw = *(const short8*)(qkv + rowbase + (size_t)(q0 + lc) * QKVN
                                      + qcol + dkk * 16 + hi * 8);
        short8 sc;
#pragma unroll
        for (int x = 0; x < 8; x++) sc[x] = (short)bf16r(fbf16(raw[x]) * s2);
        qf[dkk] = sc;
    }

    int srow = tid >> 2, sseg = tid & 3;
    uint4 sK0, sK1, sV0, sV1;
    auto STAGE_LOAD = [&](int kt) {
        int s0 = kt * 64;
        const short* kp = qkv + rowbase + (size_t)(s0 + srow) * QKVN + kcol + sseg * 16;
        sK0 = *(const uint4*)kp; sK1 = *(const uint4*)(kp + 8);
        const short* vp = vbase + (size_t)srow * T_ + s0 + sseg * 16;
        sV0 = *(const uint4*)vp; sV1 = *(const uint4*)(vp + 8);
    };
    auto STAGE_WRITE = [&](int bu) {
        *(uint4*)&Ks[bu][srow][sseg * 16]     = sK0;
        *(uint4*)&Ks[bu][srow][sseg * 16 + 8] = sK1;
        *(uint4*)&Vs[bu][srow][sseg * 16]     = sV0;
        *(uint4*)&Vs[bu][srow][sseg * 16 + 8] = sV1;
    };

    f32x16 Z16 = {0.f,0.f,0.f,0.f,0.f,0.f,0.f,0.f,0.f,0.f,0.f,0.f,0.f,0.f,0.f,0.f};
    f32x16 acc[2];
    acc[0] = Z16; acc[1] = Z16;
    float lp = 0.f;

    STAGE_LOAD(t0);
    STAGE_WRITE(t0 & 1);

    for (int kt = t0; kt < t1; kt++) {
        int bu = kt & 1;
        int s0 = kt * 64;
        bool last = (kt == nt - 1);
        __syncthreads();
        if (kt + 1 < t1) STAGE_LOAD(kt + 1);

#pragma unroll
        for (int kf = 0; kf < 2; kf++) {
            f32x16 s = Z16;
#pragma unroll
            for (int dkk = 0; dkk < 4; dkk++) {
                short8 ka = *(const short8*)&Ks[bu][kf * 32 + lc][dkk * 16 + hi * 8];
                s = __builtin_amdgcn_mfma_f32_32x32x16_bf16(ka, qf[dkk], s, 0, 0, 0);
            }
            float p[16];
            if (last) {
                int qrow = q0 + lc;
                int kb = s0 + kf * 32 + hi * 4;
#pragma unroll
                for (int reg = 0; reg < 16; reg++) {
                    int key = kb + (reg & 3) + ((reg >> 2) << 3);
                    p[reg] = (key <= qrow) ? exp2f(s[reg]) : 0.f;
                }
            } else {
#pragma unroll
                for (int reg = 0; reg < 16; reg++) p[reg] = exp2f(s[reg]);
            }
#pragma unroll
            for (int reg = 0; reg < 16; reg++) lp += p[reg];
            unsigned pk[4][2];
#pragma unroll
            for (int sb = 0; sb < 4; sb++) {
                pk[sb][0] = (unsigned)bf16r(p[4 * sb])     | ((unsigned)bf16r(p[4 * sb + 1]) << 16);
                pk[sb][1] = (unsigned)bf16r(p[4 * sb + 2]) | ((unsigned)bf16r(p[4 * sb + 3]) << 16);
            }
#pragma unroll
            for (int kk = 0; kk < 2; kk++) {
                unsigned a0 = pk[2 * kk][0], b0 = pk[2 * kk + 1][0];
                unsigned a1 = pk[2 * kk][1], b1 = pk[2 * kk + 1][1];
                plswap(a0, b0);
                plswap(a1, b1);
                union { unsigned u[4]; short8 s8; } pb;
                pb.u[0] = a0; pb.u[1] = a1; pb.u[2] = b0; pb.u[3] = b1;
#pragma unroll
                for (int df = 0; df < 2; df++) {
                    short8 va = *(const short8*)&Vs[bu][df * 32 + lc][kf * 32 + kk * 16 + hi * 8];
                    acc[df] = __builtin_amdgcn_mfma_f32_32x32x16_bf16(va, pb.s8, acc[df], 0, 0, 0);
                }
            }
        }
        if (kt + 1 < t1) STAGE_WRITE(bu ^ 1);
    }

    float lt = lp + __shfl_xor(lp, 32, 64);

    if (mode == 0) {
        float inv = 1.0f / lt;
        short* obase = attn + ((size_t)b * T_ + q0 + lc) * DOUT_ + g * 256 + w * 64;
#pragma unroll
        for (int df = 0; df < 2; df++)
#pragma unroll
            for (int sb = 0; sb < 4; sb++) {
                unsigned u0 = (unsigned)bf16r(acc[df][4 * sb] * inv) |
                              ((unsigned)bf16r(acc[df][4 * sb + 1] * inv) << 16);
                unsigned u1 = (unsigned)bf16r(acc[df][4 * sb + 2] * inv) |
                              ((unsigned)bf16r(acc[df][4 * sb + 3] * inv) << 16);
                uint2 uv = {u0, u1};
                *(uint2*)(obase + df * 32 + sb * 8 + hi * 4) = uv;
            }
    } else {
        int oid = (bg * 32 + (qt - 32)) * 2 + c;
        float* ob = opart + (size_t)oid * 8192 + lc * 256 + w * 64;
#pragma unroll
        for (int df = 0; df < 2; df++)
#pragma unroll
            for (int sb = 0; sb < 4; sb++) {
                f32x4 vv = {acc[df][4 * sb], acc[df][4 * sb + 1],
                            acc[df][4 * sb + 2], acc[df][4 * sb + 3]};
                *(f32x4*)(ob + df * 32 + sb * 8 + hi * 4) = vv;
            }
        if (hi == 0) lpart[oid * 128 + lc * 4 + w] = lt;
    }
}

// combine: out = (O0+O1) / (l0+l1) for qt>=32
__global__ __launch_bounds__(256)
void k_comb(const float* __restrict__ opart, const float* __restrict__ lpart,
            short* __restrict__ attn) {
    int id = blockIdx.x;
    int bg = id & 7, qtl = id >> 3;
    int qt = 32 + qtl;
    int b = bg & 1, g = (bg >> 1) & 3;
    int oid0 = (bg * 32 + qtl) * 2;
    int t = threadIdx.x;
    int row = t >> 3, s = t & 7;
    int head = s >> 1, colseg = s * 32;
    const float* O0 = opart + (size_t)oid0 * 8192 + row * 256 + colseg;
    const float* O1 = O0 + 8192;
    float lsum = lpart[oid0 * 128 + row * 4 + head] +
                 lpart[(oid0 + 1) * 128 + row * 4 + head];
    float inv = 1.0f / lsum;
    unsigned out[16];
#pragma unroll
    for (int i = 0; i < 8; i++) {
        float4 a = *(const float4*)(O0 + i * 4);
        float4 bb = *(const float4*)(O1 + i * 4);
        float e0 = (a.x + bb.x) * inv, e1 = (a.y + bb.y) * inv;
        float e2 = (a.z + bb.z) * inv, e3 = (a.w + bb.w) * inv;
        out[i * 2]     = (unsigned)bf16r(e0) | ((unsigned)bf16r(e1) << 16);
        out[i * 2 + 1] = (unsigned)bf16r(e2) | ((unsigned)bf16r(e3) << 16);
    }
    short* dst = attn + ((size_t)(b * T_ + qt * 32 + row)) * DOUT_ + g * 256 + colseg;
#pragma unroll
    for (int i = 0; i < 4; i++) *(uint4*)(dst + i * 8) = *(const uint4*)&out[i * 4];
}

extern "C" void kernel_launch(void* const* d_in, const int* in_sizes, int n_in,
                              void* d_out, int out_size, void* d_ws, size_t ws_size,
                              hipStream_t stream) {
    const float* x    = (const float*)d_in[0];
    const float* Wq   = (const float*)d_in[1];
    const float* Wk   = (const float*)d_in[2];
    const float* Wv   = (const float*)d_in[3];
    const float* Wo   = (const float*)d_in[4];
    const float* cosT = (const float*)d_in[5];
    const float* sinT = (const float*)d_in[6];

    char* ws = (char*)d_ws;
    short* WT    = (short*)(ws);             // [1536][1024] bf16
    short* WoT   = (short*)(ws + 3145728);   // [1024][1024] bf16
    short* QKV   = (short*)(ws + 5242880);   // [4096][1536] bf16
    short* ATT   = (short*)(ws + 17825792);  // [4096][1024] bf16
    short* VT    = (short*)(ws + 26214400);  // [8][64][2048] bf16
    float* OPART = (float*)(ws + 28311552);  // [512][32][256] f32
    float* LPART = (float*)(ws + 45088768);  // [512][128] f32
    short* XB    = (short*)(ws + 45154304);  // [4096][1024] bf16
    int split = (ws_size >= 53542912u) ? 1 : 0;

    k_xbf<<<2048, 256, 0, stream>>>(x, XB, 524288);
    k_transpose<<<dim3(16, 16), 256, 0, stream>>>(Wq, WT, 1024, 1024);
    k_transpose<<<dim3(16, 4),  256, 0, stream>>>(Wk, WT + 1024 * 1024, 1024, 256);
    k_transpose<<<dim3(16, 4),  256, 0, stream>>>(Wv, WT + 1280 * 1024, 1024, 256);
    k_transpose<<<dim3(16, 16), 256, 0, stream>>>(Wo, WoT, 1024, 1024);

    k_gemm<0, 1><<<dim3(64, 12), 256, 0, stream>>>(XB, WT, (void*)QKV,
                                                   4096, 1536, 1024, cosT, sinT);
    k_vt<<<256, 256, 0, stream>>>(QKV, VT);
    k_attn<<<split ? 768 : 512, 256, 0, stream>>>(QKV, VT, ATT, OPART, LPART, split);
    if (split) k_comb<<<256, 256, 0, stream>>>(OPART, LPART, ATT);
    k_gemm<1, 0><<<dim3(64, 8), 256, 0, stream>>>(ATT, WoT, d_out,
                                                  4096, 1024, 1024, nullptr, nullptr);
}